// Round 4
// baseline (1317.780 us; speedup 1.0000x reference)
//
#include <hip/hip_runtime.h>
#include <stdint.h>
#include <math.h>

#define DEV static __device__ __forceinline__

typedef __attribute__((ext_vector_type(8))) short bf16x8;
typedef __attribute__((ext_vector_type(4))) float f32x4;
typedef __attribute__((ext_vector_type(8))) unsigned short u16x8;
typedef __attribute__((ext_vector_type(4))) unsigned short u16x4;
typedef __attribute__((ext_vector_type(2))) unsigned int u32x2;

enum { B_ = 2, S_ = 2048, D_ = 2048, H_ = 32, HD_ = 64, N3_ = 6144, M_ = 4096 };

DEV unsigned short f2bf(float f) {
  unsigned u = __float_as_uint(f);
  u += 0x7FFFu + ((u >> 16) & 1u);
  return (unsigned short)(u >> 16);
}
DEV float bf2f(unsigned short s) { return __uint_as_float(((unsigned)s) << 16); }

DEV void load16(const void* g, void* l) {
  __builtin_amdgcn_global_load_lds((const __attribute__((address_space(1))) void*)g,
                                   (__attribute__((address_space(3))) void*)l,
                                   16, 0, 0);
}

DEV f32x4 mfma16(bf16x8 a, bf16x8 b, f32x4 c) {
  return __builtin_amdgcn_mfma_f32_16x16x32_bf16(a, b, c, 0, 0, 0);
}

// ---------------------------------------------------------------- cvt f32->bf16
__global__ __launch_bounds__(256) void cvt_bf16(const float* __restrict__ in,
                                                unsigned short* __restrict__ out, int n) {
  int i = blockIdx.x * 256 + threadIdx.x;
  if (i * 8 >= n) return;
  const float4* in4 = (const float4*)in;
  float4 a = in4[i * 2 + 0];
  float4 b = in4[i * 2 + 1];
  u16x8 o;
  o[0] = f2bf(a.x); o[1] = f2bf(a.y); o[2] = f2bf(a.z); o[3] = f2bf(a.w);
  o[4] = f2bf(b.x); o[5] = f2bf(b.y); o[6] = f2bf(b.z); o[7] = f2bf(b.w);
  *(u16x8*)(out + (size_t)i * 8) = o;
}

// ------------------------------------------- transpose f32 [K][N] -> bf16 [N][K]
__global__ __launch_bounds__(256) void transpose_bf16(const float* __restrict__ W,
                                                      unsigned short* __restrict__ Wt,
                                                      int Kg, int Ng) {
  __shared__ float tile[32][33];
  const int tn = blockIdx.x, tk = blockIdx.y;
  const int t = threadIdx.x;
  const int r = t >> 3, c4 = (t & 7) * 4;
  float4 v = *(const float4*)(W + (size_t)(tk * 32 + r) * Ng + tn * 32 + c4);
  tile[r][c4 + 0] = v.x; tile[r][c4 + 1] = v.y;
  tile[r][c4 + 2] = v.z; tile[r][c4 + 3] = v.w;
  __syncthreads();
  u16x4 o;
  o[0] = f2bf(tile[c4 + 0][r]);
  o[1] = f2bf(tile[c4 + 1][r]);
  o[2] = f2bf(tile[c4 + 2][r]);
  o[3] = f2bf(tile[c4 + 3][r]);
  *(u16x4*)(Wt + (size_t)(tn * 32 + r) * Kg + tk * 32 + c4) = o;
}

// ================= 256x256 GEMM, BK=32, 64KB LDS, 2 blocks/CU =================
// A: [Mg][Kg] bf16, BT: [Ng][Kg] bf16.  512 thr = 8 waves (2M x 4N).
// LDS 64KB: buf b at b*32KB: A 16KB | B 16KB. Row = 64B = 4 units of 16B,
// unit holds k8 = unit ^ (row&3)  (conflict-free b128 reads, linear gload dst).
// 2 phases/K-tile: P1 = 12 ds_reads + 16 MFMA (nf0-1); P2 = stage(t+2) +
// vmcnt(4) + 16 MFMA (nf2-3). Prefetch distance 2.
template <int OUT_BF16>
__global__ __launch_bounds__(512, 4) void gemm256k32(const unsigned short* __restrict__ A,
                                                     const unsigned short* __restrict__ BT,
                                                     const float* __restrict__ bias,
                                                     void* __restrict__ Cout,
                                                     int Mg, int Ng, int Kg) {
  __shared__ __align__(16) char lds[65536];
  const int tid = threadIdx.x;
  const int lane = tid & 63, w = tid >> 6;
  const int g = (lane >> 4) & 3, l16 = lane & 15;
  const int wm = w >> 2, wn = w & 3;

  // XCD-bijective swizzle (gridDim.x % 8 == 0), tm fastest.
  const int wg = (blockIdx.x & 7) * (gridDim.x >> 3) + (blockIdx.x >> 3);
  const int nTM = Mg >> 8;
  const int tm = wg % nTM, tn = wg / nTM;
  const int rb = tm * 256, cb = tn * 256;
  const int NT = Kg >> 5;

  // ---- ds_read byte offsets within a buffer
  const int sux = (g ^ (l16 & 3)) * 16;
  const int offA = (wm * 128 + l16) * 64 + sux;
  const int offB = 16384 + (wn * 64 + l16) * 64 + sux;

  // ---- staging map: thread p -> LDS row p>>2, unit p&3 (linear dest),
  //      global col8 = (p&3) ^ ((p>>2)&3) (inverse swizzle on source)
  const int rowS = tid >> 2;
  const int uS = ((tid & 3) ^ (rowS & 3)) * 8;
  const unsigned short* sA0 = A + (size_t)(rb + rowS) * Kg + uS;
  const unsigned short* sA1 = A + (size_t)(rb + 128 + rowS) * Kg + uS;
  const unsigned short* sB0 = BT + (size_t)(cb + rowS) * Kg + uS;
  const unsigned short* sB1 = BT + (size_t)(cb + 128 + rowS) * Kg + uS;
  const int dst0 = tid * 16, dst1 = 8192 + tid * 16;

#define STAGE(tgt) do { \
    char* _b = (char*)lds + (((tgt) & 1) << 15); \
    size_t _o = (size_t)(tgt) * 32; \
    load16(sA0 + _o, _b + dst0); \
    load16(sA1 + _o, _b + dst1); \
    load16(sB0 + _o, _b + 16384 + dst0); \
    load16(sB1 + _o, _b + 16384 + dst1); } while (0)

  // ---- prologue: tiles 0 and 1
  STAGE(0);
  STAGE(1);
  asm volatile("s_waitcnt vmcnt(4)" ::: "memory");
  __builtin_amdgcn_s_barrier();

  f32x4 acc[8][4] = {};

  for (int t = 0; t < NT; ++t) {
    const char* base = (const char*)lds + ((t & 1) << 15);
    // -------- P1: all 12 ds_reads for this K-tile
    bf16x8 a[8], b[4];
#pragma unroll
    for (int mf = 0; mf < 8; ++mf)
      a[mf] = *(const bf16x8*)(base + offA + mf * 1024);
#pragma unroll
    for (int nf = 0; nf < 4; ++nf)
      b[nf] = *(const bf16x8*)(base + offB + nf * 1024);
    asm volatile("s_waitcnt lgkmcnt(8)" ::: "memory");
    __builtin_amdgcn_s_barrier();
    asm volatile("s_waitcnt lgkmcnt(0)" ::: "memory");
    __builtin_amdgcn_s_setprio(1);
#pragma unroll
    for (int mf = 0; mf < 8; ++mf)
#pragma unroll
      for (int nf = 0; nf < 2; ++nf)
        acc[mf][nf] = mfma16(a[mf], b[nf], acc[mf][nf]);
    __builtin_amdgcn_s_setprio(0);
    __builtin_amdgcn_s_barrier();
    // -------- P2: stage tile t+2 (reads of this buffer fully drained above)
    if (t + 2 < NT) {
      STAGE(t + 2);
      asm volatile("s_waitcnt vmcnt(4)" ::: "memory");
    } else {
      asm volatile("s_waitcnt vmcnt(0)" ::: "memory");
    }
    __builtin_amdgcn_s_barrier();
    __builtin_amdgcn_s_setprio(1);
#pragma unroll
    for (int mf = 0; mf < 8; ++mf)
#pragma unroll
      for (int nf = 0; nf < 2; ++nf)
        acc[mf][nf + 2] = mfma16(a[mf], b[nf + 2], acc[mf][nf + 2]);
    __builtin_amdgcn_s_setprio(0);
    __builtin_amdgcn_s_barrier();
  }
#undef STAGE

  // ---- epilogue
  const int crow0 = rb + wm * 128 + g * 4;
  const int ccol0 = cb + wn * 64 + l16;
#pragma unroll
  for (int mf = 0; mf < 8; ++mf)
#pragma unroll
    for (int nf = 0; nf < 4; ++nf) {
      float bv = bias[ccol0 + nf * 16];
#pragma unroll
      for (int r = 0; r < 4; ++r) {
        int row = crow0 + mf * 16 + r;
        int col = ccol0 + nf * 16;
        float v = acc[mf][nf][r] + bv;
        if (OUT_BF16)
          ((unsigned short*)Cout)[(size_t)row * Ng + col] = f2bf(v);
        else
          ((float*)Cout)[(size_t)row * Ng + col] = v;
      }
    }
}

// ------------------------------------------------------------- GEMM C = A @ B^T
// 128x128 tile, BK=32, 32KB LDS, ~3 blocks/CU (m97 structure) — used for GEMM3.
DEV int xsw(int row) { return (row ^ (row >> 2)) & 3; }

template <int OUT_BF16>
__global__ __launch_bounds__(256) void gemm_bt(const unsigned short* __restrict__ A,
                                               const unsigned short* __restrict__ BT,
                                               const float* __restrict__ bias,
                                               void* __restrict__ Cout,
                                               int Mg, int Ng, int Kg) {
  __shared__ __align__(16) unsigned short lA[128 * 32];
  __shared__ __align__(16) unsigned short lB[128 * 32];
  const int tid = threadIdx.x;
  const int lane = tid & 63, wv = tid >> 6;
  const int g = lane >> 4, l16 = lane & 15;
  const int wr = wv >> 1, wc = wv & 1;
  const int rb = blockIdx.x * 128, cb = blockIdx.y * 128;

  f32x4 acc[4][4] = {};

  for (int k0 = 0; k0 < Kg; k0 += 32) {
    __syncthreads();
#pragma unroll
    for (int c = 0; c < 2; ++c) {
      int p = c * 256 + tid;
      int row = p >> 2;
      int k8l = (p & 3) ^ xsw(row);
      load16(A + (size_t)(rb + row) * Kg + k0 + 8 * k8l, (char*)lA + p * 16);
      load16(BT + (size_t)(cb + row) * Kg + k0 + 8 * k8l, (char*)lB + p * 16);
    }
    __syncthreads();
    bf16x8 af[4], bfr[4];
#pragma unroll
    for (int m = 0; m < 4; ++m) {
      int row = wr * 64 + m * 16 + l16;
      af[m] = *(const bf16x8*)((const char*)lA + (size_t)(row * 4 + (g ^ xsw(row))) * 16);
    }
#pragma unroll
    for (int n = 0; n < 4; ++n) {
      int row = wc * 64 + n * 16 + l16;
      bfr[n] = *(const bf16x8*)((const char*)lB + (size_t)(row * 4 + (g ^ xsw(row))) * 16);
    }
#pragma unroll
    for (int m = 0; m < 4; ++m)
#pragma unroll
      for (int n = 0; n < 4; ++n)
        acc[m][n] = mfma16(af[m], bfr[n], acc[m][n]);
  }

#pragma unroll
  for (int m = 0; m < 4; ++m)
#pragma unroll
    for (int n = 0; n < 4; ++n)
#pragma unroll
      for (int r = 0; r < 4; ++r) {
        int row = rb + wr * 64 + m * 16 + g * 4 + r;
        int col = cb + wc * 64 + n * 16 + l16;
        float v = acc[m][n][r] + bias[col];
        if (OUT_BF16)
          ((unsigned short*)Cout)[(size_t)row * Ng + col] = f2bf(v);
        else
          ((float*)Cout)[(size_t)row * Ng + col] = v;
      }
}

// -------------------------------------------------------------- RoPE (in place)
__global__ __launch_bounds__(256) void rope_kernel(unsigned short* __restrict__ qkv) {
  const int idx = blockIdx.x * 256 + threadIdx.x;  // (b, s, h)
  const int h = idx & 31;
  const int s = (idx >> 5) & (S_ - 1);
  const int b = idx >> 16;
  float cs[16], sn[16];
#pragma unroll
  for (int j = 0; j < 16; ++j) {
    float inv = exp2f(-(float)j * 0.83048202372184056f);  // log2(10000)/16
    float fr = (float)s * inv;
    sincosf(fr, &sn[j], &cs[j]);
  }
  size_t base = (size_t)(b * S_ + s) * N3_ + h * 64;
#pragma unroll
  for (int part = 0; part < 2; ++part) {  // q then k
    unsigned short* p = qkv + base + part * 2048;
    u16x8 u0 = *(u16x8*)(p + 0), u1 = *(u16x8*)(p + 8);
    u16x8 u2 = *(u16x8*)(p + 16), u3 = *(u16x8*)(p + 24);
    float a1[16], a2[16];
#pragma unroll
    for (int j = 0; j < 8; ++j) {
      a1[j] = bf2f(u0[j]); a1[j + 8] = bf2f(u1[j]);
      a2[j] = bf2f(u2[j]); a2[j + 8] = bf2f(u3[j]);
    }
    u16x8 r0, r1, r2, r3;
#pragma unroll
    for (int j = 0; j < 8; ++j) {
      r0[j] = f2bf(a1[j] * cs[j] - a2[j] * sn[j]);
      r2[j] = f2bf(a1[j] * sn[j] + a2[j] * cs[j]);
      r1[j] = f2bf(a1[j + 8] * cs[j + 8] - a2[j + 8] * sn[j + 8]);
      r3[j] = f2bf(a1[j + 8] * sn[j + 8] + a2[j + 8] * cs[j + 8]);
    }
    *(u16x8*)(p + 0) = r0;  *(u16x8*)(p + 8) = r1;
    *(u16x8*)(p + 16) = r2; *(u16x8*)(p + 24) = r3;
  }
}

// ------------------------------------------------- V transpose -> [B,H,64,S]
__global__ __launch_bounds__(256) void vtrans(const unsigned short* __restrict__ qkv,
                                              unsigned short* __restrict__ vt) {
  __shared__ unsigned short tile[64][72];
  const int s0 = blockIdx.x * 64;
  const int bh = blockIdx.y;
  const int b = bh >> 5, h = bh & 31;
  const int t = threadIdx.x;
#pragma unroll
  for (int c = 0; c < 2; ++c) {
    int sl = (c * 256 + t) >> 3, d8 = t & 7;
    u16x8 v = *(const u16x8*)(qkv + (size_t)(b * S_ + s0 + sl) * N3_ + 4096 + h * 64 + d8 * 8);
    *(u16x8*)(&tile[sl][d8 * 8]) = v;
  }
  __syncthreads();
#pragma unroll
  for (int c = 0; c < 2; ++c) {
    int dl = (c * 256 + t) >> 3, s8 = t & 7;
    u16x8 o;
#pragma unroll
    for (int j = 0; j < 8; ++j) o[j] = tile[s8 * 8 + j][dl];
    *(u16x8*)(vt + (size_t)(bh * 64 + dl) * S_ + s0 + s8 * 8) = o;
  }
}

// ----------------------------------------------------------- flash attention
DEV void stage_kv(const unsigned short* __restrict__ qkv,
                  const unsigned short* __restrict__ vt,
                  unsigned char* lds, int bS, int bh64, int hoff, int kvb, int buf, int tid) {
#pragma unroll
  for (int c = 0; c < 2; ++c) {
    int p = c * 256 + tid;
    int row = p >> 3, k8 = (p & 7) ^ (row & 7);
    load16(qkv + (size_t)(bS + kvb + row) * N3_ + 2048 + hoff + 8 * k8,
           lds + buf * 8192 + p * 16);
    load16(vt + (size_t)(bh64 + row) * S_ + kvb + 8 * k8,
           lds + 16384 + buf * 8192 + p * 16);
  }
}

__global__ __launch_bounds__(256, 3) void attn_kernel(const unsigned short* __restrict__ qkv,
                                                      const unsigned short* __restrict__ vt,
                                                      unsigned short* __restrict__ ao) {
  __shared__ __align__(16) unsigned char lds[49152];
  const int tid = threadIdx.x;
  const int lane = tid & 63, wv = tid >> 6;
  const int g = lane >> 4, l16 = lane & 15;
  const int bid = blockIdx.x;
  const int qi = 15 - (bid >> 6);
  const int t6 = bid & 63;
  const int bh = ((t6 & 7) << 3) | (t6 >> 3);
  const int b = bh >> 5, h = bh & 31;
  const int qbase = qi * 128;
  const int srow0 = qbase + wv * 32;
  const int bS = b * S_, bh64 = bh * 64, hoff = h * 64;

  bf16x8 qf[2][2];
#pragma unroll
  for (int m = 0; m < 2; ++m)
#pragma unroll
    for (int kt = 0; kt < 2; ++kt)
      qf[m][kt] = *(const bf16x8*)(qkv + (size_t)(bS + srow0 + m * 16 + l16) * N3_ +
                                   hoff + kt * 32 + g * 8);

  float mrun[2] = {-INFINITY, -INFINITY}, lrun[2] = {0.f, 0.f};
  f32x4 o[2][4] = {};
  unsigned char* pw = lds + 32768 + wv * 4096;

  const int nkv = (qbase + 128) >> 6;
  stage_kv(qkv, vt, lds, bS, bh64, hoff, 0, 0, tid);
  __syncthreads();

  for (int kb = 0; kb < nkv; ++kb) {
    const int cur = kb & 1;
    if (kb + 1 < nkv) stage_kv(qkv, vt, lds, bS, bh64, hoff, (kb + 1) << 6, cur ^ 1, tid);
    const int kvb = kb << 6;
    if (kvb <= srow0 + 31) {
      const unsigned char* kbuf = lds + cur * 8192;
      const unsigned char* vbuf = lds + 16384 + cur * 8192;

      f32x4 sc[2][4];
#pragma unroll
      for (int n = 0; n < 4; ++n) {
        int row = n * 16 + l16;
        bf16x8 kf0 = *(const bf16x8*)(kbuf + (row * 8 + ((g + 0) ^ (row & 7))) * 16);
        bf16x8 kf1 = *(const bf16x8*)(kbuf + (row * 8 + ((g + 4) ^ (row & 7))) * 16);
#pragma unroll
        for (int m = 0; m < 2; ++m) {
          f32x4 z = {};
          z = mfma16(kf0, qf[m][0], z);
          z = mfma16(kf1, qf[m][1], z);
          sc[m][n] = z;
        }
      }

      const bool boundary = (kvb + 63 > srow0);
#pragma unroll
      for (int m = 0; m < 2; ++m) {
        const int qrow = srow0 + m * 16 + l16;
        if (boundary) {
#pragma unroll
          for (int n = 0; n < 4; ++n)
#pragma unroll
            for (int r = 0; r < 4; ++r) {
              int k = kvb + n * 16 + g * 4 + r;
              if (k > qrow) sc[m][n][r] = -INFINITY;
            }
        }
        float mx = fmaxf(fmaxf(sc[m][0][0], sc[m][0][1]), fmaxf(sc[m][0][2], sc[m][0][3]));
#pragma unroll
        for (int n = 1; n < 4; ++n)
          mx = fmaxf(mx, fmaxf(fmaxf(sc[m][n][0], sc[m][n][1]), fmaxf(sc[m][n][2], sc[m][n][3])));
        mx = fmaxf(mx, __shfl_xor(mx, 16));
        mx = fmaxf(mx, __shfl_xor(mx, 32));
        float pm = mx * 0.125f;
        if (!__all(pm <= mrun[m] + 8.0f)) {
          float mn = fmaxf(mrun[m], pm);
          float al = exp2f((mrun[m] - mn) * 1.44269504f);
          mrun[m] = mn; lrun[m] *= al;
#pragma unroll
          for (int d = 0; d < 4; ++d) o[m][d] *= al;
        }
        const float mt = mrun[m] * 1.44269504f;
        float p[4][4]; float rs = 0.f;
#pragma unroll
        for (int n = 0; n < 4; ++n)
#pragma unroll
          for (int r = 0; r < 4; ++r) {
            p[n][r] = exp2f(fmaf(sc[m][n][r], 0.18033688011112042f, -mt));
            rs += p[n][r];
          }
        rs += __shfl_xor(rs, 16);
        rs += __shfl_xor(rs, 32);
        lrun[m] += rs;
#pragma unroll
        for (int n = 0; n < 4; ++n) {
          unsigned lo, hi;
          asm("v_cvt_pk_bf16_f32 %0, %1, %2" : "=v"(lo) : "v"(p[n][0]), "v"(p[n][1]));
          asm("v_cvt_pk_bf16_f32 %0, %1, %2" : "=v"(hi) : "v"(p[n][2]), "v"(p[n][3]));
          int su = (n * 4 + g) ^ ((l16 & 7) << 1);
          u32x2 wq; wq[0] = lo; wq[1] = hi;
          *(u32x2*)(pw + ((m * 16 + l16) * 16 + su) * 8) = wq;
        }
      }

      bf16x8 pf[2][2];
#pragma unroll
      for (int m = 0; m < 2; ++m)
#pragma unroll
        for (int kt = 0; kt < 2; ++kt) {
          int su = (kt * 8 + g * 2) ^ ((l16 & 7) << 1);
          pf[m][kt] = *(const bf16x8*)(pw + ((m * 16 + l16) * 16 + su) * 8);
        }
#pragma unroll
      for (int dblk = 0; dblk < 4; ++dblk) {
        int row = dblk * 16 + l16;
        bf16x8 vf0 = *(const bf16x8*)(vbuf + (row * 8 + ((g + 0) ^ (row & 7))) * 16);
        bf16x8 vf1 = *(const bf16x8*)(vbuf + (row * 8 + ((g + 4) ^ (row & 7))) * 16);
#pragma unroll
        for (int m = 0; m < 2; ++m) {
          o[m][dblk] = mfma16(vf0, pf[m][0], o[m][dblk]);
          o[m][dblk] = mfma16(vf1, pf[m][1], o[m][dblk]);
        }
      }
    }
    __syncthreads();
  }

#pragma unroll
  for (int m = 0; m < 2; ++m) {
    float inv = 1.0f / lrun[m];
    int q = srow0 + m * 16 + l16;
#pragma unroll
    for (int dblk = 0; dblk < 4; ++dblk) {
      u16x4 ov;
#pragma unroll
      for (int r = 0; r < 4; ++r) ov[r] = f2bf(o[m][dblk][r] * inv);
      *(u16x4*)(ao + (size_t)(bS + q) * D_ + hoff + dblk * 16 + g * 4) = ov;
    }
  }
}

// ---------------------------------------------------------------------- launch
extern "C" void kernel_launch(void* const* d_in, const int* in_sizes, int n_in,
                              void* d_out, int out_size, void* d_ws, size_t ws_size,
                              hipStream_t stream) {
  const float* x = (const float*)d_in[0];
  const float* Wqkv = (const float*)d_in[1];
  const float* bqkv = (const float*)d_in[2];
  const float* Wout = (const float*)d_in[3];
  const float* bout = (const float*)d_in[4];
  float* out = (float*)d_out;

  char* ws = (char*)d_ws;
  unsigned short* Xb = (unsigned short*)(ws + 0);                  // 16 MiB (reused as AO)
  unsigned short* Wqkvt = (unsigned short*)(ws + 16777216);        // 24 MiB
  unsigned short* Woutt = (unsigned short*)(ws + 41943040);        // 8 MiB
  unsigned short* QKVb = (unsigned short*)(ws + 50331648);         // 48 MiB
  unsigned short* Vt = (unsigned short*)(ws + 100663296);          // 16 MiB
  unsigned short* AO = Xb;  // Xb is dead after gemm1

  cvt_bf16<<<4096, 256, 0, stream>>>(x, Xb, M_ * D_);
  transpose_bf16<<<dim3(192, 64), 256, 0, stream>>>(Wqkv, Wqkvt, 2048, 6144);
  transpose_bf16<<<dim3(64, 64), 256, 0, stream>>>(Wout, Woutt, 2048, 2048);
  gemm256k32<1><<<384, 512, 0, stream>>>(Xb, Wqkvt, bqkv, QKVb, M_, N3_, D_);
  rope_kernel<<<512, 256, 0, stream>>>(QKVb);
  vtrans<<<dim3(32, 64), 256, 0, stream>>>(QKVb, Vt);
  attn_kernel<<<1024, 256, 0, stream>>>(QKVb, Vt, AO);
  gemm_bt<0><<<dim3(32, 16), 256, 0, stream>>>(AO, Woutt, bout, out, M_, D_, D_);
}

// Round 5
// 287.142 us; speedup vs baseline: 4.5893x; 4.5893x over previous
//
#include <hip/hip_runtime.h>
#include <stdint.h>
#include <math.h>

#define DEV static __device__ __forceinline__

typedef __attribute__((ext_vector_type(8))) short bf16x8;
typedef __attribute__((ext_vector_type(4))) float f32x4;
typedef __attribute__((ext_vector_type(8))) unsigned short u16x8;
typedef __attribute__((ext_vector_type(4))) unsigned short u16x4;
typedef __attribute__((ext_vector_type(2))) unsigned int u32x2;

enum { B_ = 2, S_ = 2048, D_ = 2048, H_ = 32, HD_ = 64, N3_ = 6144, M_ = 4096 };

DEV unsigned short f2bf(float f) {
  unsigned u = __float_as_uint(f);
  u += 0x7FFFu + ((u >> 16) & 1u);
  return (unsigned short)(u >> 16);
}
DEV float bf2f(unsigned short s) { return __uint_as_float(((unsigned)s) << 16); }

DEV void load16(const void* g, void* l) {
  __builtin_amdgcn_global_load_lds((const __attribute__((address_space(1))) void*)g,
                                   (__attribute__((address_space(3))) void*)l,
                                   16, 0, 0);
}

DEV f32x4 mfma16(bf16x8 a, bf16x8 b, f32x4 c) {
  return __builtin_amdgcn_mfma_f32_16x16x32_bf16(a, b, c, 0, 0, 0);
}

// ---------------------------------------------------------------- cvt f32->bf16
__global__ __launch_bounds__(256) void cvt_bf16(const float* __restrict__ in,
                                                unsigned short* __restrict__ out, int n) {
  int i = blockIdx.x * 256 + threadIdx.x;
  if (i * 8 >= n) return;
  const float4* in4 = (const float4*)in;
  float4 a = in4[i * 2 + 0];
  float4 b = in4[i * 2 + 1];
  u16x8 o;
  o[0] = f2bf(a.x); o[1] = f2bf(a.y); o[2] = f2bf(a.z); o[3] = f2bf(a.w);
  o[4] = f2bf(b.x); o[5] = f2bf(b.y); o[6] = f2bf(b.z); o[7] = f2bf(b.w);
  *(u16x8*)(out + (size_t)i * 8) = o;
}

// ------------------------------------------- transpose f32 [K][N] -> bf16 [N][K]
__global__ __launch_bounds__(256) void transpose_bf16(const float* __restrict__ W,
                                                      unsigned short* __restrict__ Wt,
                                                      int Kg, int Ng) {
  __shared__ float tile[32][33];
  const int tn = blockIdx.x, tk = blockIdx.y;
  const int t = threadIdx.x;
  const int r = t >> 3, c4 = (t & 7) * 4;
  float4 v = *(const float4*)(W + (size_t)(tk * 32 + r) * Ng + tn * 32 + c4);
  tile[r][c4 + 0] = v.x; tile[r][c4 + 1] = v.y;
  tile[r][c4 + 2] = v.z; tile[r][c4 + 3] = v.w;
  __syncthreads();
  u16x4 o;
  o[0] = f2bf(tile[c4 + 0][r]);
  o[1] = f2bf(tile[c4 + 1][r]);
  o[2] = f2bf(tile[c4 + 2][r]);
  o[3] = f2bf(tile[c4 + 3][r]);
  *(u16x4*)(Wt + (size_t)(tn * 32 + r) * Kg + tk * 32 + c4) = o;
}

// ===================== 256x256 GEMM, BK=64, one fat region per K-tile =========
// A: [Mg][Kg] bf16, BT: [Ng][Kg] bf16.  512 thr = 8 waves (2M x 4N), 1 blk/CU.
// LDS 128KB: buf b at b*64KB: A 32KB | B 32KB.  Row = 128B = 8 units of 16B,
// unit u holds k8 = u ^ (row&7) (2-way-free b128 reads, linear gload dest).
// Per K-tile: {24 ds_reads + 64 MFMA, compiler-interleaved} ; lgkm(0)+bar ;
// STAGE(t+2) ; vmcnt(8) (never 0 in steady state) ; bar.
// MODE 0: f32 out.  MODE 1: bf16 out + fused RoPE on cols < 4096.
template <int MODE>
__global__ __launch_bounds__(512, 2) void gemm256(const unsigned short* __restrict__ A,
                                                  const unsigned short* __restrict__ BT,
                                                  const float* __restrict__ bias,
                                                  void* __restrict__ Cout,
                                                  int Mg, int Ng, int Kg) {
  __shared__ __align__(16) char lds[131072];
  const int tid = threadIdx.x;
  const int lane = tid & 63, w = tid >> 6;
  const int g = (lane >> 4) & 3, l16 = lane & 15;
  const int wm = w >> 2, wn = w & 3;

  // XCD-bijective swizzle (gridDim.x % 8 == 0), tm fastest.
  const int wg = (blockIdx.x & 7) * (gridDim.x >> 3) + (blockIdx.x >> 3);
  const int nTM = Mg >> 8;
  const int tm = wg % nTM, tn = wg / nTM;
  const int rb = tm * 256, cb = tn * 256;
  const int NT = Kg >> 6;

  // ds_read byte offsets
  const int offA = (wm * 128 + l16) * 128;
  const int offB = 32768 + (wn * 64 + l16) * 128;
  const int su0 = ((0 + g) ^ (l16 & 7)) * 16;
  const int su1 = ((4 + g) ^ (l16 & 7)) * 16;

  // staging map: unit Uc = c*512+tid -> row Uc>>3, unit Uc&7 (linear dest),
  // global k8 = (Uc&7) ^ (row&7) (inverse swizzle on source)
  const unsigned short* sA[4]; const unsigned short* sB[4];
  int dA[4], dB[4];
#pragma unroll
  for (int c = 0; c < 4; ++c) {
    int Uc = c * 512 + tid, row = Uc >> 3, u = (Uc & 7) ^ (row & 7);
    sA[c] = A + (size_t)(rb + row) * Kg + u * 8;
    sB[c] = BT + (size_t)(cb + row) * Kg + u * 8;
    dA[c] = Uc * 16; dB[c] = 32768 + Uc * 16;
  }

  auto STAGE = [&](int t) {
    char* _b = (char*)lds + ((t & 1) << 16);
#pragma unroll
    for (int c = 0; c < 4; ++c) {
      load16(sA[c] + (size_t)t * 64, _b + dA[c]);
      load16(sB[c] + (size_t)t * 64, _b + dB[c]);
    }
  };

  // prologue: tiles 0,1 in flight; vmcnt(8) drains tile 0
  STAGE(0); STAGE(1);
  asm volatile("s_waitcnt vmcnt(8)" ::: "memory");
  __builtin_amdgcn_s_barrier();

  f32x4 acc[8][4] = {};

  for (int t = 0; t < NT; ++t) {
    const char* bs = (const char*)lds + ((t & 1) << 16);
    bf16x8 a[4][2], b[4][2];
    // reads in consumption order; compiler inserts fine-grained lgkmcnt
#pragma unroll
    for (int mf = 0; mf < 4; ++mf) {
      a[mf][0] = *(const bf16x8*)(bs + offA + mf * 2048 + su0);
      a[mf][1] = *(const bf16x8*)(bs + offA + mf * 2048 + su1);
    }
#pragma unroll
    for (int nf = 0; nf < 4; ++nf) {
      b[nf][0] = *(const bf16x8*)(bs + offB + nf * 2048 + su0);
      b[nf][1] = *(const bf16x8*)(bs + offB + nf * 2048 + su1);
    }
#pragma unroll
    for (int mf = 0; mf < 4; ++mf)
#pragma unroll
      for (int nf = 0; nf < 4; ++nf)
#pragma unroll
        for (int kh = 0; kh < 2; ++kh)
          acc[mf][nf] = mfma16(a[mf][kh], b[nf][kh], acc[mf][nf]);
    // second half of rows reuses a[] (keeps VGPR <= 256 budget)
#pragma unroll
    for (int mf = 0; mf < 4; ++mf) {
      a[mf][0] = *(const bf16x8*)(bs + offA + (mf + 4) * 2048 + su0);
      a[mf][1] = *(const bf16x8*)(bs + offA + (mf + 4) * 2048 + su1);
    }
#pragma unroll
    for (int mf = 0; mf < 4; ++mf)
#pragma unroll
      for (int nf = 0; nf < 4; ++nf)
#pragma unroll
        for (int kh = 0; kh < 2; ++kh)
          acc[mf + 4][nf] = mfma16(a[mf][kh], b[nf][kh], acc[mf + 4][nf]);

    asm volatile("s_waitcnt lgkmcnt(0)" ::: "memory");
    __builtin_amdgcn_s_barrier();
    if (t + 2 < NT) {
      STAGE(t + 2);
      asm volatile("s_waitcnt vmcnt(8)" ::: "memory");
    } else {
      asm volatile("s_waitcnt vmcnt(0)" ::: "memory");
    }
    __builtin_amdgcn_s_barrier();
  }

  // ---- epilogue (+ fused RoPE for MODE 1)
  const int crow0 = rb + wm * 128 + g * 4;
  const int ccol0 = cb + wn * 64 + l16;
  float bv[4];
#pragma unroll
  for (int nf = 0; nf < 4; ++nf) bv[nf] = bias[ccol0 + nf * 16];

  if (MODE == 1) {
    unsigned short* O = (unsigned short*)Cout;
    const bool dorot = (cb + wn * 64) < 4096;  // wave-uniform: q/k heads only
    const float inv = exp2f(-(float)l16 * 0.83048202372184056f);  // 10000^(-l16/16)
#pragma unroll
    for (int mf = 0; mf < 8; ++mf)
#pragma unroll
      for (int r = 0; r < 4; ++r) {
        int row = crow0 + mf * 16 + r;
        float v0 = acc[mf][0][r] + bv[0];
        float v1 = acc[mf][1][r] + bv[1];
        float v2 = acc[mf][2][r] + bv[2];
        float v3 = acc[mf][3][r] + bv[3];
        if (dorot) {
          float sn, cs;
          sincosf((float)(row & (S_ - 1)) * inv, &sn, &cs);
          float t0 = v0 * cs - v1 * sn;
          v1 = v0 * sn + v1 * cs;
          v0 = t0;
        }
        unsigned short* p = O + (size_t)row * Ng + ccol0;
        p[0] = f2bf(v0); p[16] = f2bf(v1); p[32] = f2bf(v2); p[48] = f2bf(v3);
      }
  } else {
    float* O = (float*)Cout;
#pragma unroll
    for (int mf = 0; mf < 8; ++mf)
#pragma unroll
      for (int r = 0; r < 4; ++r) {
        int row = crow0 + mf * 16 + r;
        float* p = O + (size_t)row * Ng + ccol0;
        p[0] = acc[mf][0][r] + bv[0];
        p[16] = acc[mf][1][r] + bv[1];
        p[32] = acc[mf][2][r] + bv[2];
        p[48] = acc[mf][3][r] + bv[3];
      }
  }
}

// ------------------------------------------------------------- GEMM C = A @ B^T
// 128x128 tile, BK=32, 32KB LDS, ~3 blocks/CU (m97 structure) — used for GEMM3.
DEV int xsw(int row) { return (row ^ (row >> 2)) & 3; }

template <int OUT_BF16>
__global__ __launch_bounds__(256) void gemm_bt(const unsigned short* __restrict__ A,
                                               const unsigned short* __restrict__ BT,
                                               const float* __restrict__ bias,
                                               void* __restrict__ Cout,
                                               int Mg, int Ng, int Kg) {
  __shared__ __align__(16) unsigned short lA[128 * 32];
  __shared__ __align__(16) unsigned short lB[128 * 32];
  const int tid = threadIdx.x;
  const int lane = tid & 63, wv = tid >> 6;
  const int g = lane >> 4, l16 = lane & 15;
  const int wr = wv >> 1, wc = wv & 1;
  const int rb = blockIdx.x * 128, cb = blockIdx.y * 128;

  f32x4 acc[4][4] = {};

  for (int k0 = 0; k0 < Kg; k0 += 32) {
    __syncthreads();
#pragma unroll
    for (int c = 0; c < 2; ++c) {
      int p = c * 256 + tid;
      int row = p >> 2;
      int k8l = (p & 3) ^ xsw(row);
      load16(A + (size_t)(rb + row) * Kg + k0 + 8 * k8l, (char*)lA + p * 16);
      load16(BT + (size_t)(cb + row) * Kg + k0 + 8 * k8l, (char*)lB + p * 16);
    }
    __syncthreads();
    bf16x8 af[4], bfr[4];
#pragma unroll
    for (int m = 0; m < 4; ++m) {
      int row = wr * 64 + m * 16 + l16;
      af[m] = *(const bf16x8*)((const char*)lA + (size_t)(row * 4 + (g ^ xsw(row))) * 16);
    }
#pragma unroll
    for (int n = 0; n < 4; ++n) {
      int row = wc * 64 + n * 16 + l16;
      bfr[n] = *(const bf16x8*)((const char*)lB + (size_t)(row * 4 + (g ^ xsw(row))) * 16);
    }
#pragma unroll
    for (int m = 0; m < 4; ++m)
#pragma unroll
      for (int n = 0; n < 4; ++n)
        acc[m][n] = mfma16(af[m], bfr[n], acc[m][n]);
  }

#pragma unroll
  for (int m = 0; m < 4; ++m)
#pragma unroll
    for (int n = 0; n < 4; ++n)
#pragma unroll
      for (int r = 0; r < 4; ++r) {
        int row = rb + wr * 64 + m * 16 + g * 4 + r;
        int col = cb + wc * 64 + n * 16 + l16;
        float v = acc[m][n][r] + bias[col];
        if (OUT_BF16)
          ((unsigned short*)Cout)[(size_t)row * Ng + col] = f2bf(v);
        else
          ((float*)Cout)[(size_t)row * Ng + col] = v;
      }
}

// ------------------------------------------------- V transpose -> [B,H,64,S]
__global__ __launch_bounds__(256) void vtrans(const unsigned short* __restrict__ qkv,
                                              unsigned short* __restrict__ vt) {
  __shared__ unsigned short tile[64][72];
  const int s0 = blockIdx.x * 64;
  const int bh = blockIdx.y;
  const int b = bh >> 5, h = bh & 31;
  const int t = threadIdx.x;
#pragma unroll
  for (int c = 0; c < 2; ++c) {
    int sl = (c * 256 + t) >> 3, d8 = t & 7;
    u16x8 v = *(const u16x8*)(qkv + (size_t)(b * S_ + s0 + sl) * N3_ + 4096 + h * 64 + d8 * 8);
    *(u16x8*)(&tile[sl][d8 * 8]) = v;
  }
  __syncthreads();
#pragma unroll
  for (int c = 0; c < 2; ++c) {
    int dl = (c * 256 + t) >> 3, s8 = t & 7;
    u16x8 o;
#pragma unroll
    for (int j = 0; j < 8; ++j) o[j] = tile[s8 * 8 + j][dl];
    *(u16x8*)(vt + (size_t)(bh * 64 + dl) * S_ + s0 + s8 * 8) = o;
  }
}

// ----------------------------------------------------------- flash attention
DEV void stage_kv(const unsigned short* __restrict__ qkv,
                  const unsigned short* __restrict__ vt,
                  unsigned char* lds, int bS, int bh64, int hoff, int kvb, int buf, int tid) {
#pragma unroll
  for (int c = 0; c < 2; ++c) {
    int p = c * 256 + tid;
    int row = p >> 3, k8 = (p & 7) ^ (row & 7);
    load16(qkv + (size_t)(bS + kvb + row) * N3_ + 2048 + hoff + 8 * k8,
           lds + buf * 8192 + p * 16);
    load16(vt + (size_t)(bh64 + row) * S_ + kvb + 8 * k8,
           lds + 16384 + buf * 8192 + p * 16);
  }
}

__global__ __launch_bounds__(256, 3) void attn_kernel(const unsigned short* __restrict__ qkv,
                                                      const unsigned short* __restrict__ vt,
                                                      unsigned short* __restrict__ ao) {
  __shared__ __align__(16) unsigned char lds[49152];
  const int tid = threadIdx.x;
  const int lane = tid & 63, wv = tid >> 6;
  const int g = lane >> 4, l16 = lane & 15;
  const int bid = blockIdx.x;
  const int qi = 15 - (bid >> 6);
  const int t6 = bid & 63;
  const int bh = ((t6 & 7) << 3) | (t6 >> 3);
  const int b = bh >> 5, h = bh & 31;
  const int qbase = qi * 128;
  const int srow0 = qbase + wv * 32;
  const int bS = b * S_, bh64 = bh * 64, hoff = h * 64;

  bf16x8 qf[2][2];
#pragma unroll
  for (int m = 0; m < 2; ++m)
#pragma unroll
    for (int kt = 0; kt < 2; ++kt)
      qf[m][kt] = *(const bf16x8*)(qkv + (size_t)(bS + srow0 + m * 16 + l16) * N3_ +
                                   hoff + kt * 32 + g * 8);

  float mrun[2] = {-INFINITY, -INFINITY}, lrun[2] = {0.f, 0.f};
  f32x4 o[2][4] = {};
  unsigned char* pw = lds + 32768 + wv * 4096;

  const int nkv = (qbase + 128) >> 6;
  stage_kv(qkv, vt, lds, bS, bh64, hoff, 0, 0, tid);
  __syncthreads();

  for (int kb = 0; kb < nkv; ++kb) {
    const int cur = kb & 1;
    if (kb + 1 < nkv) stage_kv(qkv, vt, lds, bS, bh64, hoff, (kb + 1) << 6, cur ^ 1, tid);
    const int kvb = kb << 6;
    if (kvb <= srow0 + 31) {
      const unsigned char* kbuf = lds + cur * 8192;
      const unsigned char* vbuf = lds + 16384 + cur * 8192;

      f32x4 sc[2][4];
#pragma unroll
      for (int n = 0; n < 4; ++n) {
        int row = n * 16 + l16;
        bf16x8 kf0 = *(const bf16x8*)(kbuf + (row * 8 + ((g + 0) ^ (row & 7))) * 16);
        bf16x8 kf1 = *(const bf16x8*)(kbuf + (row * 8 + ((g + 4) ^ (row & 7))) * 16);
#pragma unroll
        for (int m = 0; m < 2; ++m) {
          f32x4 z = {};
          z = mfma16(kf0, qf[m][0], z);
          z = mfma16(kf1, qf[m][1], z);
          sc[m][n] = z;
        }
      }

      const bool boundary = (kvb + 63 > srow0);
#pragma unroll
      for (int m = 0; m < 2; ++m) {
        const int qrow = srow0 + m * 16 + l16;
        if (boundary) {
#pragma unroll
          for (int n = 0; n < 4; ++n)
#pragma unroll
            for (int r = 0; r < 4; ++r) {
              int k = kvb + n * 16 + g * 4 + r;
              if (k > qrow) sc[m][n][r] = -INFINITY;
            }
        }
        float mx = fmaxf(fmaxf(sc[m][0][0], sc[m][0][1]), fmaxf(sc[m][0][2], sc[m][0][3]));
#pragma unroll
        for (int n = 1; n < 4; ++n)
          mx = fmaxf(mx, fmaxf(fmaxf(sc[m][n][0], sc[m][n][1]), fmaxf(sc[m][n][2], sc[m][n][3])));
        mx = fmaxf(mx, __shfl_xor(mx, 16));
        mx = fmaxf(mx, __shfl_xor(mx, 32));
        float pm = mx * 0.125f;
        if (!__all(pm <= mrun[m] + 8.0f)) {
          float mn = fmaxf(mrun[m], pm);
          float al = exp2f((mrun[m] - mn) * 1.44269504f);
          mrun[m] = mn; lrun[m] *= al;
#pragma unroll
          for (int d = 0; d < 4; ++d) o[m][d] *= al;
        }
        const float mt = mrun[m] * 1.44269504f;
        float p[4][4]; float rs = 0.f;
#pragma unroll
        for (int n = 0; n < 4; ++n)
#pragma unroll
          for (int r = 0; r < 4; ++r) {
            p[n][r] = exp2f(fmaf(sc[m][n][r], 0.18033688011112042f, -mt));
            rs += p[n][r];
          }
        rs += __shfl_xor(rs, 16);
        rs += __shfl_xor(rs, 32);
        lrun[m] += rs;
#pragma unroll
        for (int n = 0; n < 4; ++n) {
          unsigned lo, hi;
          asm("v_cvt_pk_bf16_f32 %0, %1, %2" : "=v"(lo) : "v"(p[n][0]), "v"(p[n][1]));
          asm("v_cvt_pk_bf16_f32 %0, %1, %2" : "=v"(hi) : "v"(p[n][2]), "v"(p[n][3]));
          int su = (n * 4 + g) ^ ((l16 & 7) << 1);
          u32x2 wq; wq[0] = lo; wq[1] = hi;
          *(u32x2*)(pw + ((m * 16 + l16) * 16 + su) * 8) = wq;
        }
      }

      bf16x8 pf[2][2];
#pragma unroll
      for (int m = 0; m < 2; ++m)
#pragma unroll
        for (int kt = 0; kt < 2; ++kt) {
          int su = (kt * 8 + g * 2) ^ ((l16 & 7) << 1);
          pf[m][kt] = *(const bf16x8*)(pw + ((m * 16 + l16) * 16 + su) * 8);
        }
#pragma unroll
      for (int dblk = 0; dblk < 4; ++dblk) {
        int row = dblk * 16 + l16;
        bf16x8 vf0 = *(const bf16x8*)(vbuf + (row * 8 + ((g + 0) ^ (row & 7))) * 16);
        bf16x8 vf1 = *(const bf16x8*)(vbuf + (row * 8 + ((g + 4) ^ (row & 7))) * 16);
#pragma unroll
        for (int m = 0; m < 2; ++m) {
          o[m][dblk] = mfma16(vf0, pf[m][0], o[m][dblk]);
          o[m][dblk] = mfma16(vf1, pf[m][1], o[m][dblk]);
        }
      }
    }
    __syncthreads();
  }

#pragma unroll
  for (int m = 0; m < 2; ++m) {
    float inv = 1.0f / lrun[m];
    int q = srow0 + m * 16 + l16;
#pragma unroll
    for (int dblk = 0; dblk < 4; ++dblk) {
      u16x4 ov;
#pragma unroll
      for (int r = 0; r < 4; ++r) ov[r] = f2bf(o[m][dblk][r] * inv);
      *(u16x4*)(ao + (size_t)(bS + q) * D_ + hoff + dblk * 16 + g * 4) = ov;
    }
  }
}

// ---------------------------------------------------------------------- launch
extern "C" void kernel_launch(void* const* d_in, const int* in_sizes, int n_in,
                              void* d_out, int out_size, void* d_ws, size_t ws_size,
                              hipStream_t stream) {
  const float* x = (const float*)d_in[0];
  const float* Wqkv = (const float*)d_in[1];
  const float* bqkv = (const float*)d_in[2];
  const float* Wout = (const float*)d_in[3];
  const float* bout = (const float*)d_in[4];
  float* out = (float*)d_out;

  char* ws = (char*)d_ws;
  unsigned short* Xb = (unsigned short*)(ws + 0);                  // 16 MiB (reused as AO)
  unsigned short* Wqkvt = (unsigned short*)(ws + 16777216);        // 24 MiB
  unsigned short* Woutt = (unsigned short*)(ws + 41943040);        // 8 MiB
  unsigned short* QKVb = (unsigned short*)(ws + 50331648);         // 48 MiB
  unsigned short* Vt = (unsigned short*)(ws + 100663296);          // 16 MiB
  unsigned short* AO = Xb;  // Xb is dead after gemm1

  cvt_bf16<<<4096, 256, 0, stream>>>(x, Xb, M_ * D_);
  transpose_bf16<<<dim3(192, 64), 256, 0, stream>>>(Wqkv, Wqkvt, 2048, 6144);
  transpose_bf16<<<dim3(64, 64), 256, 0, stream>>>(Wout, Woutt, 2048, 2048);
  gemm256<1><<<384, 512, 0, stream>>>(Xb, Wqkvt, bqkv, QKVb, M_, N3_, D_);
  vtrans<<<dim3(32, 64), 256, 0, stream>>>(QKVb, Vt);
  attn_kernel<<<1024, 256, 0, stream>>>(QKVb, Vt, AO);
  gemm_bt<0><<<dim3(32, 16), 256, 0, stream>>>(AO, Woutt, bout, out, M_, D_, D_);
}